// Round 3
// baseline (137.588 us; speedup 1.0000x reference)
//
#include <hip/hip_runtime.h>

// VectorQuantizer, bf16-MFMA distance GEMM, fragment-order LDS, fused epilogue.
// x [32,64,4096] f32, emb [512,64] f32. N = 131072 rows (n = b*4096+t), D=64, K=512.
// dist(n,k) = ||e_k||^2 - 2*x_n.e_k ; out[0..N*64) = emb[argmin][:] (fp32 exact);
// out[N*64] = 1.25 * mean((q_flat - x_linear)^2).

#define VQ_OUTQ 8388608

typedef __attribute__((ext_vector_type(8))) short short8;
typedef __attribute__((ext_vector_type(4))) float f32x4;

// pack two fp32 -> two bf16 (round-half-up; bias negligible vs bf16 noise class)
__device__ __forceinline__ unsigned pk_bf16(float a, float b) {
    union { float f; unsigned u; } x, y; x.f = a; y.f = b;
    return ((y.u + 0x8000u) & 0xFFFF0000u) | ((x.u + 0x8000u) >> 16);
}

__global__ __launch_bounds__(256, 2) void vq_main(
    const float* __restrict__ x,
    const float* __restrict__ emb,
    float* __restrict__ qout,
    double* __restrict__ lacc,
    unsigned* __restrict__ cnt)
{
    // emb bf16 in MFMA-fragment order: slot s = (ct*2+kc)*64 + lane, 16 B each.
    __shared__ __align__(16) short ebfrag[4096 * 8];   // 65536 B
    __shared__ float cks[512];                         // ||e_k||^2 fp32
    __shared__ int   idxs[256];
    __shared__ float wsum[4];

    const int tid  = threadIdx.x;
    const int lane = tid & 63, wave = tid >> 6;
    const int m = lane & 15, quad = lane >> 4;
    const int wbase = wave << 6;

    const int b  = blockIdx.x >> 4;
    const int t0 = (blockIdx.x & 15) << 8;             // 256-row t-tile

    // ---- A-fragments: x direct global -> bf16 VGPR (issued first, overlaps staging)
    // frag (rt,kc): lane holds x[b][d = kc*32 + quad*8 + j][t0 + wbase + rt*16 + m]
    short8 a[4][2];
    {
        const float* __restrict__ xa =
            x + (size_t)b * 262144 + (size_t)(t0 + wbase + m);
        #pragma unroll
        for (int rt = 0; rt < 4; ++rt) {
            #pragma unroll
            for (int kc = 0; kc < 2; ++kc) {
                const float* __restrict__ p =
                    xa + rt * 16 + (size_t)(kc * 32 + quad * 8) * 4096;
                float f[8];
                #pragma unroll
                for (int j = 0; j < 8; ++j) f[j] = p[(size_t)j * 4096];
                union { short8 s8; unsigned u[4]; } w;
                w.u[0] = pk_bf16(f[0], f[1]);
                w.u[1] = pk_bf16(f[2], f[3]);
                w.u[2] = pk_bf16(f[4], f[5]);
                w.u[3] = pk_bf16(f[6], f[7]);
                a[rt][kc] = w.s8;
            }
        }
    }

    // ---- stage emb -> fragment-order bf16 LDS (conflict-free contiguous writes)
    #pragma unroll
    for (int it = 0; it < 16; ++it) {
        const int s  = it * 256 + tid;
        const int l  = s & 63;
        const int kc = (s >> 6) & 1;
        const int ct = s >> 7;
        const int qs = l >> 4, ms = l & 15;
        const float* __restrict__ er =
            emb + (ct * 16 + ms) * 64 + kc * 32 + qs * 8;
        float4 p0 = *(const float4*)er;
        float4 p1 = *(const float4*)(er + 4);
        union { short8 s8; unsigned u[4]; } w;
        w.u[0] = pk_bf16(p0.x, p0.y);
        w.u[1] = pk_bf16(p0.z, p0.w);
        w.u[2] = pk_bf16(p1.x, p1.y);
        w.u[3] = pk_bf16(p1.z, p1.w);
        *(short8*)&ebfrag[s * 8] = w.s8;
    }

    // ---- codeword norms fp32 (2 rows/thread)
    #pragma unroll
    for (int it = 0; it < 2; ++it) {
        const int k = it * 256 + tid;
        const float4* __restrict__ er = (const float4*)emb + k * 16;
        float c = 0.f;
        #pragma unroll
        for (int i = 0; i < 16; ++i) {
            float4 e = er[i];
            c = fmaf(e.x, e.x, c); c = fmaf(e.y, e.y, c);
            c = fmaf(e.z, e.z, c); c = fmaf(e.w, e.w, c);
        }
        cks[k] = c;
    }
    __syncthreads();

    // ---- MFMA distance + running argmin (wave owns 64 rows)
    float best[4][4]; int bid[4][4];
    #pragma unroll
    for (int rt = 0; rt < 4; ++rt)
        #pragma unroll
        for (int r = 0; r < 4; ++r) { best[rt][r] = 3.0e38f; bid[rt][r] = 0; }

    const short8* __restrict__ eb8 = (const short8*)ebfrag;
    #pragma unroll 2
    for (int ct = 0; ct < 32; ++ct) {
        short8 b0 = eb8[ct * 128 + lane];        // kc=0, lane*16B contiguous
        short8 b1 = eb8[ct * 128 + 64 + lane];   // kc=1
        const int cod = (ct << 4) + m;
        float ck = cks[cod];
        #pragma unroll
        for (int rt = 0; rt < 4; ++rt) {
            f32x4 acc = {0.f, 0.f, 0.f, 0.f};
            acc = __builtin_amdgcn_mfma_f32_16x16x32_bf16(a[rt][0], b0, acc, 0, 0, 0);
            acc = __builtin_amdgcn_mfma_f32_16x16x32_bf16(a[rt][1], b1, acc, 0, 0, 0);
            #pragma unroll
            for (int r = 0; r < 4; ++r) {
                float dist = fmaf(-2.f, acc[r], ck);
                if (dist < best[rt][r]) { best[rt][r] = dist; bid[rt][r] = cod; }
            }
        }
    }

    // ---- cross-lane argmin over the 16 m-lanes (tie -> lowest index)
    #pragma unroll
    for (int rt = 0; rt < 4; ++rt) {
        #pragma unroll
        for (int r = 0; r < 4; ++r) {
            float bv = best[rt][r]; int bi = bid[rt][r];
            #pragma unroll
            for (int mm = 1; mm < 16; mm <<= 1) {
                float ov = __shfl_xor(bv, mm, 64);
                int   oi = __shfl_xor(bi, mm, 64);
                if (ov < bv || (ov == bv && oi < bi)) { bv = ov; bi = oi; }
            }
            if (m == 0) idxs[wbase + rt * 16 + (quad << 2) + r] = bi;
        }
    }
    __syncthreads();

    // ---- epilogue: quantized rows (exact fp32 emb) + fused loss vs linear x
    {
        const int bi = idxs[tid];
        const size_t n = ((size_t)b << 12) + t0 + tid;
        const float4* __restrict__ ebr = (const float4*)emb + bi * 16;
        const float4* __restrict__ xl  = (const float4*)x + n * 16;
        float4* __restrict__ qo = (float4*)qout + n * 16;
        float ls = 0.f;
        #pragma unroll
        for (int i = 0; i < 16; ++i) {
            float4 q = ebr[i];
            float4 xr = xl[i];
            qo[i] = q;
            float dx = q.x - xr.x, dy = q.y - xr.y;
            float dz = q.z - xr.z, dw = q.w - xr.w;
            ls = fmaf(dx, dx, ls); ls = fmaf(dy, dy, ls);
            ls = fmaf(dz, dz, ls); ls = fmaf(dw, dw, ls);
        }
        #pragma unroll
        for (int off = 32; off > 0; off >>= 1)
            ls += __shfl_down(ls, off, 64);
        if (lane == 0) wsum[wave] = ls;
    }
    __syncthreads();

    // ---- loss: block partial -> device atomic; last block writes final value
    if (tid == 0) {
        double s = (double)wsum[0] + (double)wsum[1]
                 + (double)wsum[2] + (double)wsum[3];
        atomicAdd(lacc, s);
        __threadfence();
        unsigned t = atomicAdd(cnt, 1u);
        if (t == 511u) {
            __threadfence();
            double tot = atomicAdd(lacc, 0.0);   // all 512 adds complete
            qout[VQ_OUTQ] = (float)(1.25 * tot / 8388608.0);
        }
    }
}

extern "C" void kernel_launch(void* const* d_in, const int* in_sizes, int n_in,
                              void* d_out, int out_size, void* d_ws, size_t ws_size,
                              hipStream_t stream)
{
    const float* x   = (const float*)d_in[0];
    const float* emb = (const float*)d_in[1];
    float* out = (float*)d_out;
    double* acc = (double*)d_ws;
    unsigned* cnt = (unsigned*)((char*)d_ws + 8);

    hipMemsetAsync(d_ws, 0, 16, stream);
    vq_main<<<dim3(512), dim3(256), 0, stream>>>(x, emb, out, acc, cnt);
}